// Round 8
// baseline (433.222 us; speedup 1.0000x reference)
//
#include <hip/hip_runtime.h>
#include <hip/hip_bf16.h>
#include <stdint.h>

// ---------------------------------------------------------------------------
// HeadAttention: Q=xq*W^T+b, K=xk*W^T+b, V=xv*W^T+b (same W,b),
// O = softmax(causal(Q K^T / 32)) V.    B=4, S=2048, E=1024, fp32 in/out.
// R13 = R11 qkv/cvt (best measured: 91 us, 0 conflicts) + scores/pv
// rebuilt as BARRIER-FREE direct-from-L2 loops (m169 lesson: LDS-staging
// L2-resident data is pure overhead).  Per 64-K step per wave: 16 frag
// loads (global b128, 8 moving row-pointers + imm offset) + 32 MFMA;
// register double-buffer, unroll-by-2 (NT always even), no __shared__,
// no barriers, no vmcnt drains.  Grids/mappings/epilogues = R11 verbatim:
// scores 768 blocks (544 active lower-tri), pv 512 blocks pair-balanced.
// Working sets: scores Q panel 256KB x8-shared + 8 K panels 2MB per XCD;
// pv P panel 512KB x8-shared per XCD -> L2-resident (4MB/XCD).
// ---------------------------------------------------------------------------

typedef __attribute__((ext_vector_type(8))) short bf16x8;
typedef __attribute__((ext_vector_type(4))) float floatx4;

#define DEVI static __device__ __forceinline__

static constexpr int S_ = 2048;
static constexpr int E_ = 1024;
static constexpr int BATCH = 4;
static constexpr int N4X = 8192 * 1024 / 4;  // float4 count per X input

DEVI unsigned short f2b(float f) {
  union { float f; unsigned u; } v; v.f = f;
  return (unsigned short)((v.u + 0x7FFFu + ((v.u >> 16) & 1u)) >> 16); // RNE
}

DEVI void async_load16(const void* g, void* l) {
  __builtin_amdgcn_global_load_lds(
      (__attribute__((address_space(1))) void*)(void*)(g),
      (__attribute__((address_space(3))) void*)(l),
      16, 0, 0);
}

// ---- zero-conflict [ROWS][64] LDS tile machinery (qkv only) ---------------

template <int ROWS, int NTHR>
DEVI void stage64(const unsigned short* __restrict__ src, unsigned short* ls,
                  int ld, int tid) {
#pragma unroll
  for (int j = 0; j < ROWS * 8 / NTHR; ++j) {
    const int u = tid + j * NTHR;
    const int row = u >> 3, slot = u & 7;
    async_load16(src + (size_t)row * ld + ((slot ^ (row & 7)) << 3),
                 ls + u * 8);
  }
}

DEVI bf16x8 ldfrag64(const unsigned short* ls, int r, int c) {
  return *(const bf16x8*)(ls + r * 64 + ((c ^ (r & 7)) << 3));
}

DEVI void mfma_tile64(const unsigned short* lsA, const unsigned short* lsB,
                      int m0, int n0, int lrow, int g, floatx4 (&acc)[4][4]) {
#pragma unroll
  for (int ks = 0; ks < 2; ++ks) {
    bf16x8 af[4], bfr[4];
#pragma unroll
    for (int i = 0; i < 4; ++i)
      af[i] = ldfrag64(lsA, m0 + i * 16 + lrow, ks * 4 + g);
#pragma unroll
    for (int i = 0; i < 4; ++i)
      bfr[i] = ldfrag64(lsB, n0 + i * 16 + lrow, ks * 4 + g);
#pragma unroll
    for (int mi = 0; mi < 4; ++mi)
#pragma unroll
      for (int ni = 0; ni < 4; ++ni)
        acc[mi][ni] = __builtin_amdgcn_mfma_f32_16x16x32_bf16(
            af[mi], bfr[ni], acc[mi][ni], 0, 0, 0);
  }
}

// ---- barrier-free direct-from-L2 K-loop (scores / pv) ---------------------

DEVI void ld_frags(const unsigned short* (&pa)[4], const unsigned short* (&pb)[4],
                   bf16x8 (&x0)[4], bf16x8 (&x1)[4], bf16x8 (&y0)[4],
                   bf16x8 (&y1)[4]) {
#pragma unroll
  for (int i = 0; i < 4; ++i) {
    x0[i] = *(const bf16x8*)(pa[i]);
    x1[i] = *(const bf16x8*)(pa[i] + 32);  // ks=1: +32 bf16 = +64B
    y0[i] = *(const bf16x8*)(pb[i]);
    y1[i] = *(const bf16x8*)(pb[i] + 32);
    pa[i] += 64;  // next 64-K tile
    pb[i] += 64;
  }
}

DEVI void mfma32(const bf16x8 (&x0)[4], const bf16x8 (&x1)[4],
                 const bf16x8 (&y0)[4], const bf16x8 (&y1)[4],
                 floatx4 (&acc)[4][4]) {
#pragma unroll
  for (int mi = 0; mi < 4; ++mi)
#pragma unroll
    for (int ni = 0; ni < 4; ++ni)
      acc[mi][ni] = __builtin_amdgcn_mfma_f32_16x16x32_bf16(
          x0[mi], y0[ni], acc[mi][ni], 0, 0, 0);
#pragma unroll
  for (int mi = 0; mi < 4; ++mi)
#pragma unroll
    for (int ni = 0; ni < 4; ++ni)
      acc[mi][ni] = __builtin_amdgcn_mfma_f32_16x16x32_bf16(
          x1[mi], y1[ni], acc[mi][ni], 0, 0, 0);
}

// NT must be EVEN (scores: 16; pv: (bm+1)*2).  Frag elem j =
// Mat[base + i*16 + (lane&15)][kt*64 + ks*32 + (lane>>4)*8 + j].
DEVI void kloop_l2(const unsigned short* __restrict__ A, int lda,
                   const unsigned short* __restrict__ Bt, int ldb, int NT,
                   int m0, int n0, int lane, floatx4 (&acc)[4][4]) {
  const int lrow = lane & 15, g = lane >> 4;
  const unsigned short* pa[4];
  const unsigned short* pb[4];
#pragma unroll
  for (int i = 0; i < 4; ++i) {
    pa[i] = A + (size_t)(m0 + i * 16 + lrow) * lda + g * 8;
    pb[i] = Bt + (size_t)(n0 + i * 16 + lrow) * ldb + g * 8;
  }
  bf16x8 a0[4], a1[4], b0[4], b1[4], c0[4], c1[4], d0[4], d1[4];
  ld_frags(pa, pb, a0, a1, b0, b1);
  for (int kt = 0; kt + 2 <= NT; kt += 2) {
    ld_frags(pa, pb, c0, c1, d0, d1);     // tile kt+1 in flight
    mfma32(a0, a1, b0, b1, acc);          // compute tile kt
    if (kt + 2 < NT) ld_frags(pa, pb, a0, a1, b0, b1);  // tile kt+2
    mfma32(c0, c1, d0, d1, acc);          // compute tile kt+1
  }
}

// fp32 -> bf16 convert: xq|xk|xv -> Xb, Wq -> Wb, one dispatch
__global__ void cvt_all(const float* __restrict__ xq,
                        const float* __restrict__ xk,
                        const float* __restrict__ xv,
                        const float* __restrict__ Wq,
                        unsigned short* __restrict__ Xb,
                        unsigned short* __restrict__ Wb) {
  int i = blockIdx.x * blockDim.x + threadIdx.x;
  const float4* src;
  ushort4* dst;
  if (i < 3 * N4X) {
    int seg = i / N4X, off = i - seg * N4X;
    const float* s = (seg == 0) ? xq : (seg == 1) ? xk : xv;
    src = (const float4*)s + off;
    dst = (ushort4*)(Xb + (size_t)seg * 8192 * 1024) + off;
  } else {
    int off = i - 3 * N4X;  // [0, 1024*1024/4)
    src = (const float4*)Wq + off;
    dst = (ushort4*)Wb + off;
  }
  float4 v = *src;
  ushort4 o;
  o.x = f2b(v.x); o.y = f2b(v.y); o.z = f2b(v.z); o.w = f2b(v.w);
  *dst = o;
}

// ---------------------------------------------------------------------------
// Fused QKV linear (R11 verbatim): C = Xb * Wb^T + bias.  Xb = [3*8192,1024].
// 1536 blocks; XCD swizzle: 8 bn sharing an A-tile at stride-8 => same XCD
// L2.  V (input 2) stored transposed: Vt[b][e][s].
// ---------------------------------------------------------------------------
__global__ __launch_bounds__(256) void gemm_qkv(
    const unsigned short* __restrict__ Xb, const unsigned short* __restrict__ Wb,
    const float* __restrict__ bias, unsigned short* __restrict__ Qb,
    unsigned short* __restrict__ Kb, unsigned short* __restrict__ Vt) {
  __shared__ __align__(16) unsigned short lsA[128 * 64];
  __shared__ __align__(16) unsigned short lsB[128 * 64];
  const int l = blockIdx.x;
  const int xcd = l & 7, i = l >> 3;
  const int bn = i & 7;
  const int bmg = xcd * 24 + (i >> 3);  // [0,192): global 128-row tile
  const int input = bmg / 64, bm = bmg % 64;
  const unsigned short* A = Xb + (size_t)bmg * 128 * 1024;
  const unsigned short* W = Wb + (size_t)bn * 128 * 1024;

  const int tid = threadIdx.x;
  const int lane = tid & 63, wave = tid >> 6;
  const int m0 = (wave >> 1) * 64, n0 = (wave & 1) * 64;
  const int lrow = lane & 15, g = lane >> 4;

  floatx4 acc[4][4] = {};
  for (int kt = 0; kt < 16; ++kt) {  // 16 barriers, 64 K each
    if (kt) __syncthreads();
    stage64<128, 256>(A + kt * 64, lsA, 1024, tid);
    stage64<128, 256>(W + kt * 64, lsB, 1024, tid);
    __syncthreads();
    mfma_tile64(lsA, lsB, m0, n0, lrow, g, acc);
  }

  unsigned short* C = (input == 0) ? Qb : (input == 1) ? Kb : Vt;
  const int rb = (lane >> 4) * 4;  // C/D: col=lane&15, row=(lane>>4)*4+reg
#pragma unroll
  for (int mi = 0; mi < 4; ++mi)
#pragma unroll
    for (int ni = 0; ni < 4; ++ni) {
      int gcol = bn * 128 + n0 + ni * 16 + lrow;
      float bv = bias[gcol];
#pragma unroll
      for (int r = 0; r < 4; ++r) {
        int grow = bm * 128 + m0 + mi * 16 + rb + r;
        unsigned short val = f2b(acc[mi][ni][r] + bv);
        if (input == 2) {
          int b = grow >> 11, s = grow & 2047;
          C[((size_t)b * 1024 + gcol) * 2048 + s] = val;
        } else {
          C[(size_t)grow * 1024 + gcol] = val;
        }
      }
    }
}

// ---------------------------------------------------------------------------
// Scores+exp: P[z][q,k] = exp(Q.K/32) (unnorm, bf16; 0 where k>q), and
// l[z*2048+q] += row sums (atomic).  Lower-tri 128-blocks only; swizzle: 768
// ids, 2 XCDs/batch, groups of 8 bn share a Q tile per XCD.  (R11 mapping;
// K-loop is barrier-free direct-from-L2.)
// ---------------------------------------------------------------------------
__global__ __launch_bounds__(256) void gemm_scores_exp(
    const unsigned short* __restrict__ Qb,
    const unsigned short* __restrict__ Kb, unsigned short* __restrict__ P,
    float* __restrict__ lsum) {
  const int l = blockIdx.x;
  const int xcd = l & 7, k = l >> 3;
  const int m = k & 7, gl = k >> 3;
  const int gg = xcd * 12 + gl;
  const int z = gg / 24, r0 = gg % 24;
  const int bm = (r0 < 8) ? r0 : 8 + ((r0 - 8) >> 1);
  const int bn = ((r0 < 8) ? 0 : ((r0 - 8) & 1)) * 8 + m;
  if (bn > bm) return;

  const unsigned short* A = Qb + ((size_t)z * S_ + bm * 128) * E_;
  const unsigned short* Bt = Kb + ((size_t)z * S_ + bn * 128) * E_;
  const int tid = threadIdx.x;
  const int lane = tid & 63, wave = tid >> 6;
  const int m0 = (wave >> 1) * 64, n0 = (wave & 1) * 64;

  floatx4 acc[4][4] = {};
  kloop_l2(A, E_, Bt, E_, 16, m0, n0, lane, acc);

  const int lrow = lane & 15;
  const int rb = (lane >> 4) * 4;
  const bool diag = (bm == bn);
#pragma unroll
  for (int mi = 0; mi < 4; ++mi)
#pragma unroll
    for (int r = 0; r < 4; ++r) {
      const int grow = bm * 128 + m0 + mi * 16 + rb + r;
      float rsum = 0.f;
#pragma unroll
      for (int ni = 0; ni < 4; ++ni) {
        const int gcol = bn * 128 + n0 + ni * 16 + lrow;
        float p = __expf(acc[mi][ni][r] * 0.03125f);
        if (diag && gcol > grow) p = 0.f;
        P[((size_t)z * S_ + grow) * S_ + gcol] = f2b(p);
        rsum += p;
      }
      // reduce over the 16 lanes holding this row's 64 columns
#pragma unroll
      for (int off = 1; off < 16; off <<= 1) rsum += __shfl_xor(rsum, off);
      if ((lane & 15) == 0) atomicAdd(&lsum[z * S_ + grow], rsum);
    }
}

// ---------------------------------------------------------------------------
// PV: out[z][q,e] = (P V) / l[q], K truncated at (bm+1)*128.
// 512 blocks, pair-balanced: xcd handles bm in {15-xcd, xcd} for all 4 z;
// 8 bn per row-tile share the P tile on one XCD.  (R11 mapping; K-loop is
// barrier-free direct-from-L2.)
// ---------------------------------------------------------------------------
__global__ __launch_bounds__(256) void gemm_pv(
    const unsigned short* __restrict__ Pb,
    const unsigned short* __restrict__ Vt, const float* __restrict__ lsum,
    float* __restrict__ Out) {
  const int l = blockIdx.x;
  const int xcd = l & 7, i = l >> 3;
  const int bn = i & 7, j = i >> 3;
  const int z = j >> 1;
  const int bm = (j & 1) ? xcd : 15 - xcd;

  const unsigned short* A = Pb + ((size_t)z * S_ + bm * 128) * S_;
  const unsigned short* Bt = Vt + ((size_t)z * E_ + bn * 128) * S_;
  float* C = Out + (size_t)z * S_ * E_;
  const int tid = threadIdx.x;
  const int lane = tid & 63, wave = tid >> 6;
  const int m0 = (wave >> 1) * 64, n0 = (wave & 1) * 64;

  floatx4 acc[4][4] = {};
  const int NT = (bm + 1) * 2;  // 64-K steps, covers k <= bm*128+127 (even)
  kloop_l2(A, S_, Bt, S_, NT, m0, n0, lane, acc);

  const int lrow = lane & 15;
  const int rb = (lane >> 4) * 4;
#pragma unroll
  for (int mi = 0; mi < 4; ++mi)
#pragma unroll
    for (int r = 0; r < 4; ++r) {
      const int grow = bm * 128 + m0 + mi * 16 + rb + r;
      const float inv = 1.0f / lsum[z * S_ + grow];
#pragma unroll
      for (int ni = 0; ni < 4; ++ni) {
        const int gcol = bn * 128 + n0 + ni * 16 + lrow;
        C[(size_t)grow * E_ + gcol] = acc[mi][ni][r] * inv;
      }
    }
}

// ---------------------------------------------------------------------------
extern "C" void kernel_launch(void* const* d_in, const int* in_sizes, int n_in,
                              void* d_out, int out_size, void* d_ws,
                              size_t ws_size, hipStream_t stream) {
  (void)in_sizes; (void)n_in; (void)out_size; (void)ws_size;
  const float* xq = (const float*)d_in[0];
  const float* xk = (const float*)d_in[1];
  const float* xv = (const float*)d_in[2];
  const float* Wq = (const float*)d_in[3];
  const float* bq = (const float*)d_in[4];
  // d_in[5] att_mask: exact triu(k=1) causal mask, handled analytically.
  float* out = (float*)d_out;

  // workspace (<= 114 MB used):
  //  [0,48M):  Xb (bf16 3*8192*1024) during cvt+QKV; then reused as
  //            P (bf16 4*2048*2048 = 32M) by scores/pv.
  //  [48,50M): Wb  [50,66M): Qb  [66,82M): Kb  [82,98M): Vt
  //  [98M, 98M+32K): l (fp32 row sums)
  unsigned short* base16 = (unsigned short*)d_ws;
  unsigned short* Xb = base16;
  unsigned short* P = base16;
  unsigned short* Wb = base16 + (size_t)24 * 1024 * 1024;  // +48MB
  unsigned short* Qb = Wb + (size_t)1024 * 1024;
  unsigned short* Kb = Qb + (size_t)8192 * 1024;
  unsigned short* Vt = Kb + (size_t)8192 * 1024;
  float* lsum = (float*)(Vt + (size_t)8192 * 1024);  // +98MB, 32KB

  hipMemsetAsync(lsum, 0, BATCH * S_ * sizeof(float), stream);

  const int n4tot = 3 * N4X + 1024 * 1024 / 4;
  cvt_all<<<n4tot / 256, 256, 0, stream>>>(xq, xk, xv, Wq, Xb, Wb);

  gemm_qkv<<<1536, 256, 0, stream>>>(Xb, Wb, bq, Qb, Kb, Vt);
  gemm_scores_exp<<<768, 256, 0, stream>>>(Qb, Kb, P, lsum);
  gemm_pv<<<512, 256, 0, stream>>>(P, Vt, lsum, out);
}

// Round 9
// 278.298 us; speedup vs baseline: 1.5567x; 1.5567x over previous
//
#include <hip/hip_runtime.h>
#include <hip/hip_bf16.h>
#include <stdint.h>

// ---------------------------------------------------------------------------
// HeadAttention: Q=xq*W^T+b, K=xk*W^T+b, V=xv*W^T+b (same W,b),
// O = softmax(causal(Q K^T / 32)) V.    B=4, S=2048, E=1024, fp32 in/out.
// R14 = R11 kernels re-packed for occupancy (inner loops/epilogues verbatim):
//   gemm_qk:       Q,K projections only. 1024 blocks (4/CU exact).
//   gemm_scores_v: ONE dispatch, 1280 blocks = 544 live scores tiles
//                  (R11 decode on ids [0,768), dead ids return) + 512
//                  V-projection tiles (ids [768,1280)).  V is independent
//                  of scores, so it fills the scores tail: 5 blocks/CU
//                  (LDS cap), 20 waves/CU vs scores-alone 2.1 blocks/CU.
//   gemm_pv, cvt_all: R11 verbatim.
// Inner loop everywhere: zero-conflict [rows][64] swizzled LDS (chunk c of
// row r at slot c^(r&7); linear global_load_lds dest + inverse-swizzled
// source), 2-barrier __syncthreads K-loop (best measured: 91us qkv, 0
// bank conflicts).
// ---------------------------------------------------------------------------

typedef __attribute__((ext_vector_type(8))) short bf16x8;
typedef __attribute__((ext_vector_type(4))) float floatx4;

#define DEVI static __device__ __forceinline__

static constexpr int S_ = 2048;
static constexpr int E_ = 1024;
static constexpr int BATCH = 4;
static constexpr int N4X = 8192 * 1024 / 4;  // float4 count per X input

DEVI unsigned short f2b(float f) {
  union { float f; unsigned u; } v; v.f = f;
  return (unsigned short)((v.u + 0x7FFFu + ((v.u >> 16) & 1u)) >> 16); // RNE
}

DEVI void async_load16(const void* g, void* l) {
  __builtin_amdgcn_global_load_lds(
      (__attribute__((address_space(1))) void*)(void*)(g),
      (__attribute__((address_space(3))) void*)(l),
      16, 0, 0);
}

// ---- zero-conflict [ROWS][64] LDS tile machinery --------------------------

template <int ROWS, int NTHR>
DEVI void stage64(const unsigned short* __restrict__ src, unsigned short* ls,
                  int ld, int tid) {
#pragma unroll
  for (int j = 0; j < ROWS * 8 / NTHR; ++j) {
    const int u = tid + j * NTHR;
    const int row = u >> 3, slot = u & 7;
    async_load16(src + (size_t)row * ld + ((slot ^ (row & 7)) << 3),
                 ls + u * 8);
  }
}

DEVI bf16x8 ldfrag64(const unsigned short* ls, int r, int c) {
  return *(const bf16x8*)(ls + r * 64 + ((c ^ (r & 7)) << 3));
}

// 32 MFMAs on one staged 64-K A/B tile pair (two 32-K halves).
DEVI void mfma_tile64(const unsigned short* lsA, const unsigned short* lsB,
                      int m0, int n0, int lrow, int g, floatx4 (&acc)[4][4]) {
#pragma unroll
  for (int ks = 0; ks < 2; ++ks) {
    bf16x8 af[4], bfr[4];
#pragma unroll
    for (int i = 0; i < 4; ++i)
      af[i] = ldfrag64(lsA, m0 + i * 16 + lrow, ks * 4 + g);
#pragma unroll
    for (int i = 0; i < 4; ++i)
      bfr[i] = ldfrag64(lsB, n0 + i * 16 + lrow, ks * 4 + g);
#pragma unroll
    for (int mi = 0; mi < 4; ++mi)
#pragma unroll
      for (int ni = 0; ni < 4; ++ni)
        acc[mi][ni] = __builtin_amdgcn_mfma_f32_16x16x32_bf16(
            af[mi], bfr[ni], acc[mi][ni], 0, 0, 0);
  }
}

// fp32 -> bf16 convert: xq|xk|xv -> Xb, Wq -> Wb, one dispatch
__global__ void cvt_all(const float* __restrict__ xq,
                        const float* __restrict__ xk,
                        const float* __restrict__ xv,
                        const float* __restrict__ Wq,
                        unsigned short* __restrict__ Xb,
                        unsigned short* __restrict__ Wb) {
  int i = blockIdx.x * blockDim.x + threadIdx.x;
  const float4* src;
  ushort4* dst;
  if (i < 3 * N4X) {
    int seg = i / N4X, off = i - seg * N4X;
    const float* s = (seg == 0) ? xq : (seg == 1) ? xk : xv;
    src = (const float4*)s + off;
    dst = (ushort4*)(Xb + (size_t)seg * 8192 * 1024) + off;
  } else {
    int off = i - 3 * N4X;  // [0, 1024*1024/4)
    src = (const float4*)Wq + off;
    dst = (ushort4*)Wb + off;
  }
  float4 v = *src;
  ushort4 o;
  o.x = f2b(v.x); o.y = f2b(v.y); o.z = f2b(v.z); o.w = f2b(v.w);
  *dst = o;
}

// ---------------------------------------------------------------------------
// Q,K projections: C = Xb[0:2] * Wb^T + bias.  1024 blocks (4/CU exact).
// XCD swizzle: 8 bn sharing an A-tile at stride-8 => same XCD L2.
// ---------------------------------------------------------------------------
__global__ __launch_bounds__(256) void gemm_qk(
    const unsigned short* __restrict__ Xb, const unsigned short* __restrict__ Wb,
    const float* __restrict__ bias, unsigned short* __restrict__ Qb,
    unsigned short* __restrict__ Kb) {
  __shared__ __align__(16) unsigned short lsA[128 * 64];
  __shared__ __align__(16) unsigned short lsB[128 * 64];
  const int l = blockIdx.x;
  const int xcd = l & 7, i = l >> 3;    // i in [0,128)
  const int bn = i & 7;
  const int bmg = xcd * 16 + (i >> 3);  // [0,128): Q tiles 0-63, K 64-127
  const int input = bmg >> 6, bm = bmg & 63;
  const unsigned short* A = Xb + (size_t)bmg * 128 * 1024;
  const unsigned short* W = Wb + (size_t)bn * 128 * 1024;

  const int tid = threadIdx.x;
  const int lane = tid & 63, wave = tid >> 6;
  const int m0 = (wave >> 1) * 64, n0 = (wave & 1) * 64;
  const int lrow = lane & 15, g = lane >> 4;

  floatx4 acc[4][4] = {};
  for (int kt = 0; kt < 16; ++kt) {  // 16 barriers, 64 K each
    if (kt) __syncthreads();
    stage64<128, 256>(A + kt * 64, lsA, 1024, tid);
    stage64<128, 256>(W + kt * 64, lsB, 1024, tid);
    __syncthreads();
    mfma_tile64(lsA, lsB, m0, n0, lrow, g, acc);
  }

  unsigned short* C = input ? Kb : Qb;
  const int rb = (lane >> 4) * 4;  // C/D: col=lane&15, row=(lane>>4)*4+reg
#pragma unroll
  for (int mi = 0; mi < 4; ++mi)
#pragma unroll
    for (int ni = 0; ni < 4; ++ni) {
      int gcol = bn * 128 + n0 + ni * 16 + lrow;
      float bv = bias[gcol];
#pragma unroll
      for (int r = 0; r < 4; ++r) {
        int grow = bm * 128 + m0 + mi * 16 + rb + r;
        C[(size_t)grow * 1024 + gcol] = f2b(acc[mi][ni][r] + bv);
      }
    }
}

// ---------------------------------------------------------------------------
// Fused scores + V-projection, one dispatch, 1280 blocks (5/CU, LDS cap).
//   ids [0,768):  scores lower-tri tiles (R11 decode verbatim; dead ids with
//                 bn>bm return).  P[z][q,k] = exp(Q.K/32) (unnorm bf16, 0
//                 where k>q); lsum[z*2048+q] += row sums (atomic).
//   ids [768,1280): V = Xb[2] * Wb^T + bias, stored transposed Vt[b][e][s].
// Both parts: 16 x 64-K iterations, identical inner loop.
// ---------------------------------------------------------------------------
__global__ __launch_bounds__(256) void gemm_scores_v(
    const unsigned short* __restrict__ Xb,
    const unsigned short* __restrict__ Wb, const float* __restrict__ bias,
    const unsigned short* __restrict__ Qb,
    const unsigned short* __restrict__ Kb, unsigned short* __restrict__ P,
    float* __restrict__ lsum, unsigned short* __restrict__ Vt) {
  __shared__ __align__(16) unsigned short lsA[128 * 64];
  __shared__ __align__(16) unsigned short lsB[128 * 64];
  const int l = blockIdx.x;
  const int tid = threadIdx.x;
  const int lane = tid & 63, wave = tid >> 6;
  const int m0 = (wave >> 1) * 64, n0 = (wave & 1) * 64;
  const int lrow = lane & 15, g = lane >> 4;
  const int rb = (lane >> 4) * 4;

  if (l < 768) {
    // ---------------- scores tile (R11 decode verbatim) ----------------
    const int xcd = l & 7, k = l >> 3;
    const int m = k & 7, gl = k >> 3;
    const int gg = xcd * 12 + gl;
    const int z = gg / 24, r0 = gg % 24;
    const int bm = (r0 < 8) ? r0 : 8 + ((r0 - 8) >> 1);
    const int bn = ((r0 < 8) ? 0 : ((r0 - 8) & 1)) * 8 + m;
    if (bn > bm) return;

    const unsigned short* A = Qb + ((size_t)z * S_ + bm * 128) * E_;
    const unsigned short* Bt = Kb + ((size_t)z * S_ + bn * 128) * E_;

    floatx4 acc[4][4] = {};
    for (int kt = 0; kt < 16; ++kt) {
      if (kt) __syncthreads();
      stage64<128, 256>(A + kt * 64, lsA, E_, tid);
      stage64<128, 256>(Bt + kt * 64, lsB, E_, tid);
      __syncthreads();
      mfma_tile64(lsA, lsB, m0, n0, lrow, g, acc);
    }

    const bool diag = (bm == bn);
#pragma unroll
    for (int mi = 0; mi < 4; ++mi)
#pragma unroll
      for (int r = 0; r < 4; ++r) {
        const int grow = bm * 128 + m0 + mi * 16 + rb + r;
        float rsum = 0.f;
#pragma unroll
        for (int ni = 0; ni < 4; ++ni) {
          const int gcol = bn * 128 + n0 + ni * 16 + lrow;
          float p = __expf(acc[mi][ni][r] * 0.03125f);
          if (diag && gcol > grow) p = 0.f;
          P[((size_t)z * S_ + grow) * S_ + gcol] = f2b(p);
          rsum += p;
        }
#pragma unroll
        for (int off = 1; off < 16; off <<= 1) rsum += __shfl_xor(rsum, off);
        if ((lane & 15) == 0) atomicAdd(&lsum[z * S_ + grow], rsum);
      }
  } else {
    // ---------------- V-projection tile (R11 qkv input==2 path) --------
    const int lv = l - 768;
    const int xcd = lv & 7, i = lv >> 3;  // i in [0,64)
    const int bn = i & 7;
    const int bm = xcd * 8 + (i >> 3);    // [0,64): 128-row tile of xv
    const unsigned short* A = Xb + (size_t)(128 + bm) * 128 * 1024;
    const unsigned short* W = Wb + (size_t)bn * 128 * 1024;

    floatx4 acc[4][4] = {};
    for (int kt = 0; kt < 16; ++kt) {
      if (kt) __syncthreads();
      stage64<128, 256>(A + kt * 64, lsA, 1024, tid);
      stage64<128, 256>(W + kt * 64, lsB, 1024, tid);
      __syncthreads();
      mfma_tile64(lsA, lsB, m0, n0, lrow, g, acc);
    }

#pragma unroll
    for (int mi = 0; mi < 4; ++mi)
#pragma unroll
      for (int ni = 0; ni < 4; ++ni) {
        int gcol = bn * 128 + n0 + ni * 16 + lrow;
        float bv = bias[gcol];
#pragma unroll
        for (int r = 0; r < 4; ++r) {
          int grow = bm * 128 + m0 + mi * 16 + rb + r;
          int b = grow >> 11, s = grow & 2047;
          Vt[((size_t)b * 1024 + gcol) * 2048 + s] = f2b(acc[mi][ni][r] + bv);
        }
      }
  }
}

// ---------------------------------------------------------------------------
// PV (R11 verbatim): out[z][q,e] = (P V) / l[q], K truncated at (bm+1)*128.
// 512 blocks, pair-balanced: xcd handles bm in {15-xcd, xcd} for all 4 z;
// 8 bn per row-tile share the P tile on one XCD.
// ---------------------------------------------------------------------------
__global__ __launch_bounds__(256) void gemm_pv(
    const unsigned short* __restrict__ Pb,
    const unsigned short* __restrict__ Vt, const float* __restrict__ lsum,
    float* __restrict__ Out) {
  __shared__ __align__(16) unsigned short lsA[128 * 64];
  __shared__ __align__(16) unsigned short lsB[128 * 64];
  const int l = blockIdx.x;
  const int xcd = l & 7, i = l >> 3;
  const int bn = i & 7, j = i >> 3;
  const int z = j >> 1;
  const int bm = (j & 1) ? xcd : 15 - xcd;

  const unsigned short* A = Pb + ((size_t)z * S_ + bm * 128) * S_;
  const unsigned short* Bt = Vt + ((size_t)z * E_ + bn * 128) * S_;
  float* C = Out + (size_t)z * S_ * E_;
  const int tid = threadIdx.x;
  const int lane = tid & 63, wave = tid >> 6;
  const int m0 = (wave >> 1) * 64, n0 = (wave & 1) * 64;
  const int lrow = lane & 15, g = lane >> 4;

  floatx4 acc[4][4] = {};
  const int nKK = (bm + 1) * 2;  // 64-K steps, covers k <= bm*128+127
  for (int kt = 0; kt < nKK; ++kt) {
    if (kt) __syncthreads();
    stage64<128, 256>(A + kt * 64, lsA, S_, tid);
    stage64<128, 256>(Bt + kt * 64, lsB, S_, tid);
    __syncthreads();
    mfma_tile64(lsA, lsB, m0, n0, lrow, g, acc);
  }

  const int rb = (lane >> 4) * 4;
#pragma unroll
  for (int mi = 0; mi < 4; ++mi)
#pragma unroll
    for (int r = 0; r < 4; ++r) {
      const int grow = bm * 128 + m0 + mi * 16 + rb + r;
      const float inv = 1.0f / lsum[z * S_ + grow];
#pragma unroll
      for (int ni = 0; ni < 4; ++ni) {
        const int gcol = bn * 128 + n0 + ni * 16 + lrow;
        C[(size_t)grow * E_ + gcol] = acc[mi][ni][r] * inv;
      }
    }
}

// ---------------------------------------------------------------------------
extern "C" void kernel_launch(void* const* d_in, const int* in_sizes, int n_in,
                              void* d_out, int out_size, void* d_ws,
                              size_t ws_size, hipStream_t stream) {
  (void)in_sizes; (void)n_in; (void)out_size; (void)ws_size;
  const float* xq = (const float*)d_in[0];
  const float* xk = (const float*)d_in[1];
  const float* xv = (const float*)d_in[2];
  const float* Wq = (const float*)d_in[3];
  const float* bq = (const float*)d_in[4];
  // d_in[5] att_mask: exact triu(k=1) causal mask, handled analytically.
  float* out = (float*)d_out;

  // workspace (<= 114 MB used):
  //  [0,48M):  Xb (bf16 3*8192*1024) during cvt+projections; then reused as
  //            P (bf16 4*2048*2048 = 32M) by scores/pv.  NOTE: P overlaps
  //            only Xb[0:2] (Q,K inputs, consumed before scores writes);
  //            Xb[2] (xv) lives at [32M,48M) -- P is exactly 32M, no clash.
  //  [48,50M): Wb  [50,66M): Qb  [66,82M): Kb  [82,98M): Vt
  //  [98M, 98M+32K): l (fp32 row sums)
  unsigned short* base16 = (unsigned short*)d_ws;
  unsigned short* Xb = base16;
  unsigned short* P = base16;
  unsigned short* Wb = base16 + (size_t)24 * 1024 * 1024;  // +48MB
  unsigned short* Qb = Wb + (size_t)1024 * 1024;
  unsigned short* Kb = Qb + (size_t)8192 * 1024;
  unsigned short* Vt = Kb + (size_t)8192 * 1024;
  float* lsum = (float*)(Vt + (size_t)8192 * 1024);  // +98MB, 32KB

  hipMemsetAsync(lsum, 0, BATCH * S_ * sizeof(float), stream);

  const int n4tot = 3 * N4X + 1024 * 1024 / 4;
  cvt_all<<<n4tot / 256, 256, 0, stream>>>(xq, xk, xv, Wq, Xb, Wb);

  gemm_qk<<<1024, 256, 0, stream>>>(Xb, Wb, bq, Qb, Kb);
  gemm_scores_v<<<1280, 256, 0, stream>>>(Xb, Wb, bq, Qb, Kb, P, lsum, Vt);
  gemm_pv<<<512, 256, 0, stream>>>(P, Vt, lsum, out);
}